// Round 1
// baseline (114.617 us; speedup 1.0000x reference)
//
#include <hip/hip_runtime.h>
#include <math.h>

// Problem constants (from reference): x is (32, 4096, 128) fp32.
#define BATCH   32
#define SEQLEN  4096
#define DK      128
#define NPAIR   (DK / 2)          // 64 rotation pairs per row
#define NQUAD   (DK / 4)          // 32 float4 per row

// log2(10000.0)
#define LOG2_THETA 13.287712379549449f

// ---------------------------------------------------------------------------
// Kernel 1: build the (cos, sin) table: tab[s*NPAIR + i] = {cos(a), sin(a)}
// where a = pos[s] * theta^(-2i/d).  4096*64 = 262144 entries = 2 MiB.
// ---------------------------------------------------------------------------
__global__ void rope_build_table(const int* __restrict__ token_positions,
                                 float2* __restrict__ tab) {
    int t = blockIdx.x * blockDim.x + threadIdx.x;   // [0, SEQLEN*NPAIR)
    int i = t & (NPAIR - 1);                         // pair index
    int s = t >> 6;                                  // seq position index
    float p = (float)token_positions[s];
    // exponent = (2*i)/d ; inv_freq = theta^(-exponent) = 2^(-exponent*log2(theta))
    float e = (float)(2 * i) * (1.0f / (float)DK);
    float inv_freq = exp2f(-e * LOG2_THETA);
    float ang = p * inv_freq;
    float sn, cs;
    sincosf(ang, &sn, &cs);
    tab[t] = make_float2(cs, sn);
}

// ---------------------------------------------------------------------------
// Kernel 2: streaming apply. One thread = one float4 (= 2 rotation pairs).
// Table is read as float4 (cos0, sin0, cos1, sin1).
// ---------------------------------------------------------------------------
__global__ void rope_apply(const float4* __restrict__ x,
                           const float4* __restrict__ tab,  // alias of float2 table
                           float4* __restrict__ out,
                           int total_quads) {
    int t = blockIdx.x * blockDim.x + threadIdx.x;
    if (t >= total_quads) return;
    int j   = t & (NQUAD - 1);       // which quad within the row
    int row = t >> 5;                // row index in [0, BATCH*SEQLEN)
    int s   = row & (SEQLEN - 1);    // seq position
    float4 v = x[t];
    float4 cz = tab[s * NQUAD + j];  // cos0, sin0, cos1, sin1
    float4 o;
    o.x = v.x * cz.x - v.y * cz.y;
    o.y = v.x * cz.y + v.y * cz.x;
    o.z = v.z * cz.z - v.w * cz.w;
    o.w = v.z * cz.w + v.w * cz.z;
    out[t] = o;
}

// ---------------------------------------------------------------------------
// Fallback: fully fused (computes sincos inline) in case ws is too small.
// ---------------------------------------------------------------------------
__global__ void rope_fused(const float4* __restrict__ x,
                           const int* __restrict__ token_positions,
                           float4* __restrict__ out,
                           int total_quads) {
    int t = blockIdx.x * blockDim.x + threadIdx.x;
    if (t >= total_quads) return;
    int j   = t & (NQUAD - 1);
    int row = t >> 5;
    int s   = row & (SEQLEN - 1);
    float p = (float)token_positions[s];
    float4 v = x[t];
    // pair indices i0 = 2j, i1 = 2j+1
    float e0 = (float)(4 * j)     * (1.0f / (float)DK);
    float e1 = (float)(4 * j + 2) * (1.0f / (float)DK);
    float a0 = p * exp2f(-e0 * LOG2_THETA);
    float a1 = p * exp2f(-e1 * LOG2_THETA);
    float s0, c0, s1, c1;
    sincosf(a0, &s0, &c0);
    sincosf(a1, &s1, &c1);
    float4 o;
    o.x = v.x * c0 - v.y * s0;
    o.y = v.x * s0 + v.y * c0;
    o.z = v.z * c1 - v.w * s1;
    o.w = v.z * s1 + v.w * c1;
    out[t] = o;
}

extern "C" void kernel_launch(void* const* d_in, const int* in_sizes, int n_in,
                              void* d_out, int out_size, void* d_ws, size_t ws_size,
                              hipStream_t stream) {
    const float* x              = (const float*)d_in[0];
    const int*   token_positions = (const int*)d_in[1];
    float*       out            = (float*)d_out;

    const int total       = out_size;          // 32*4096*128 = 16,777,216
    const int total_quads = total / 4;         // 4,194,304
    const size_t tab_bytes = (size_t)SEQLEN * NPAIR * sizeof(float2); // 2 MiB

    if (ws_size >= tab_bytes) {
        float2* tab = (float2*)d_ws;
        {
            int n = SEQLEN * NPAIR;            // 262144
            dim3 block(256), grid((n + 255) / 256);
            rope_build_table<<<grid, block, 0, stream>>>(token_positions, tab);
        }
        {
            dim3 block(256), grid((total_quads + 255) / 256);
            rope_apply<<<grid, block, 0, stream>>>((const float4*)x,
                                                   (const float4*)tab,
                                                   (float4*)out, total_quads);
        }
    } else {
        dim3 block(256), grid((total_quads + 255) / 256);
        rope_fused<<<grid, block, 0, stream>>>((const float4*)x, token_positions,
                                               (float4*)out, total_quads);
    }
}

// Round 2
// 112.210 us; speedup vs baseline: 1.0214x; 1.0214x over previous
//
#include <hip/hip_runtime.h>
#include <math.h>

// Problem constants: x is (32, 4096, 128) fp32, token_positions = arange(4096).
#define BATCH    32
#define SEQLEN   4096
#define DK       128
#define NQUAD    (DK / 4)              // 32 float4 per row
#define ROWQUADS (SEQLEN * NQUAD)      // 131072 float4 per batch (= 2^17)
#define BPT      8                     // batches processed per thread

#define LOG2_THETA 13.287712379549449f // log2(10000)
#define INV_2PI    0.15915494309189535f

// Single fused streaming kernel.
// Thread t -> (s, j, batch-chunk). Computes cos/sin once via hardware
// v_sin_f32/v_cos_f32 (revolutions + explicit fract range reduction),
// applies to BPT batches. All global accesses are coalesced float4.
__global__ __launch_bounds__(256) void rope_fused_fast(
    const float4* __restrict__ x,
    const int*    __restrict__ pos,
    float4*       __restrict__ out)
{
    int t     = blockIdx.x * blockDim.x + threadIdx.x;  // [0, 4 * 131072)
    int pid   = t & (ROWQUADS - 1);                     // (s, j) pair id
    int chunk = t >> 17;                                // which group of 8 batches
    int j     = pid & (NQUAD - 1);                      // quad index within row
    int s     = pid >> 5;                               // seq position

    float p = (float)pos[s];

    // pair indices i0 = 2j, i1 = 2j+1; exponent = 2*i/DK
    float e0 = (float)j * (1.0f / 32.0f);               // 4j/128
    float e1 = e0 + (2.0f / 128.0f);
    float f0 = __builtin_amdgcn_exp2f(-e0 * LOG2_THETA); // theta^(-e0)
    float f1 = __builtin_amdgcn_exp2f(-e1 * LOG2_THETA);

    // angle in revolutions, explicit fract for valid v_sin/v_cos range
    float r0 = p * f0 * INV_2PI;
    float r1 = p * f1 * INV_2PI;
    r0 = r0 - floorf(r0);
    r1 = r1 - floorf(r1);
    float s0 = __builtin_amdgcn_sinf(r0);   // sin(r * 2*pi)
    float c0 = __builtin_amdgcn_cosf(r0);
    float s1 = __builtin_amdgcn_sinf(r1);
    float c1 = __builtin_amdgcn_cosf(r1);

    int base = pid + chunk * (BPT * ROWQUADS);
    #pragma unroll
    for (int i = 0; i < BPT; ++i) {
        int idx = base + i * ROWQUADS;
        float4 v = x[idx];
        float4 o;
        o.x = v.x * c0 - v.y * s0;
        o.y = v.x * s0 + v.y * c0;
        o.z = v.z * c1 - v.w * s1;
        o.w = v.z * s1 + v.w * c1;
        out[idx] = o;
    }
}

extern "C" void kernel_launch(void* const* d_in, const int* in_sizes, int n_in,
                              void* d_out, int out_size, void* d_ws, size_t ws_size,
                              hipStream_t stream) {
    const float* x   = (const float*)d_in[0];
    const int*   pos = (const int*)d_in[1];
    float*       out = (float*)d_out;

    // 524288 threads = 2048 blocks x 256; exact, no tail.
    const int nthreads = (BATCH / BPT) * ROWQUADS;
    dim3 block(256), grid(nthreads / 256);
    rope_fused_fast<<<grid, block, 0, stream>>>((const float4*)x, pos, (float4*)out);
}